// Round 4
// baseline (42005.658 us; speedup 1.0000x reference)
//
#include <hip/hip_runtime.h>
#include <math.h>

constexpr int Bn = 64;
constexpr int Tn = 512;
constexpr int Hn = 768;
constexpr int RTn = Bn * Tn;               // 32768 rows

// workspace offsets (in floats)
constexpr size_t OFF_XP   = 0;
constexpr size_t OFF_H12  = OFF_XP  + (size_t)RTn * Hn;
constexpr size_t OFF_TAGX = OFF_H12 + (size_t)RTn * Hn;
constexpr size_t OFF_C12  = OFF_TAGX + (size_t)RTn;
constexpr size_t OFF_H1B0 = OFF_C12  + Hn;
constexpr size_t OFF_H1B1 = OFF_H1B0 + (size_t)Bn * Hn;
constexpr size_t OFF_H2B0 = OFF_H1B1 + (size_t)Bn * Hn;
constexpr size_t OFF_H2B1 = OFF_H2B0 + (size_t)Bn * Hn;
constexpr size_t OFF_BAR  = OFF_H2B1 + (size_t)Bn * Hn;   // 4 groups x 64 ints

// ---------------------------------------------------------------------------
__global__ void __launch_bounds__(256) c12_kernel(const float* __restrict__ Whh12,
                                                  const float* __restrict__ hinit,
                                                  const float* __restrict__ b12,
                                                  float* __restrict__ c12) {
    int j = blockIdx.x * 256 + threadIdx.x;
    if (j >= Hn) return;
    float s = b12[j];
    const float* row = Whh12 + (size_t)j * Hn;
    for (int e = 0; e < Hn; ++e) s += row[e] * hinit[e];
    c12[j] = s;
}

// ---------------------------------------------------------------------------
__global__ void __launch_bounds__(256) tagx_kernel(const float* __restrict__ bert,
                                                   const float* __restrict__ Wtag,
                                                   const float* __restrict__ btag,
                                                   float* __restrict__ tagx) {
    int r = blockIdx.x * 4 + (threadIdx.x >> 6);
    int lane = threadIdx.x & 63;
    const float* wx = Wtag + 2 * Hn;
    const float* row = bert + (size_t)r * Hn;
    float s = 0.f;
    for (int e = lane; e < Hn; e += 64) s += row[e] * wx[e];
    #pragma unroll
    for (int m = 1; m < 64; m <<= 1) s += __shfl_xor(s, m, 64);
    if (lane == 0) tagx[r] = s + btag[0];
}

// ---------------------------------------------------------------------------
// Precompute GEMM (fp32): xp11 and tanh'ed h12_seq.
__global__ void __launch_bounds__(256) gemm_pre(const float* __restrict__ bert,
                                                const float* __restrict__ Wih11,
                                                const float* __restrict__ Wih12,
                                                const float* __restrict__ b11,
                                                const float* __restrict__ c12,
                                                float* __restrict__ xp,
                                                float* __restrict__ h12) {
    constexpr int BM = 128, BN = 64, BK = 16;
    __shared__ float As[BK][BM];
    __shared__ float Ws[BK][BN];
    const int bid = blockIdx.x;
    const int mt = bid / 24, nt = bid % 24;
    const int r0 = mt * BM;
    const int n0 = nt * BN;
    const bool second = (n0 >= Hn);
    const float* W = second ? Wih12 : Wih11;
    const int jbase = second ? (n0 - Hn) : n0;
    const int tid = threadIdx.x;
    const int ty = tid >> 4, tx = tid & 15;
    const int lrow = tid >> 1, lhalf = (tid & 1) * 8;
    const int wjl = tid & 63, wkk = tid >> 6;
    float acc[8][4] = {};
    for (int e0 = 0; e0 < Hn; e0 += BK) {
        float4 av0 = *(const float4*)(bert + (size_t)(r0 + lrow) * Hn + e0 + lhalf);
        float4 av1 = *(const float4*)(bert + (size_t)(r0 + lrow) * Hn + e0 + lhalf + 4);
        float4 wv  = *(const float4*)(W + (size_t)(jbase + wjl) * Hn + e0 + wkk * 4);
        As[lhalf + 0][lrow] = av0.x; As[lhalf + 1][lrow] = av0.y;
        As[lhalf + 2][lrow] = av0.z; As[lhalf + 3][lrow] = av0.w;
        As[lhalf + 4][lrow] = av1.x; As[lhalf + 5][lrow] = av1.y;
        As[lhalf + 6][lrow] = av1.z; As[lhalf + 7][lrow] = av1.w;
        Ws[wkk * 4 + 0][wjl] = wv.x; Ws[wkk * 4 + 1][wjl] = wv.y;
        Ws[wkk * 4 + 2][wjl] = wv.z; Ws[wkk * 4 + 3][wjl] = wv.w;
        __syncthreads();
        #pragma unroll
        for (int k = 0; k < BK; ++k) {
            float a[8], w[4];
            *(float4*)&a[0] = *(const float4*)&As[k][ty * 8];
            *(float4*)&a[4] = *(const float4*)&As[k][ty * 8 + 4];
            *(float4*)&w[0] = *(const float4*)&Ws[k][tx * 4];
            #pragma unroll
            for (int ii = 0; ii < 8; ++ii)
                #pragma unroll
                for (int jj = 0; jj < 4; ++jj)
                    acc[ii][jj] += a[ii] * w[jj];
        }
        __syncthreads();
    }
    #pragma unroll
    for (int ii = 0; ii < 8; ++ii) {
        size_t r = (size_t)(r0 + ty * 8 + ii);
        if (!second) {
            #pragma unroll
            for (int jj = 0; jj < 4; ++jj) {
                int n = n0 + tx * 4 + jj;
                xp[r * Hn + n] = acc[ii][jj] + b11[n];
            }
        } else {
            #pragma unroll
            for (int jj = 0; jj < 4; ++jj) {
                int n = n0 - Hn + tx * 4 + jj;
                h12[r * Hn + n] = tanhf(acc[ii][jj] + c12[n]);
            }
        }
    }
}

// ---------------------------------------------------------------------------
// Scan v2: 192 blocks = 4 batch-groups(16 batches) x 48 col-groups(16 cols),
// 1024 threads (16 waves, 4/SIMD). Thread (j=lane&15, ks=wv*4+(lane>>4)) holds
// W[col][ks*12..+12) for 3 matrices in 9 float4 regs. Wave w owns batch w for
// gate + epilogue (tag in-register, fp32 carry in lanes<16). Sync = custom
// per-group barrier (48 blocks, device-scope atomic + monotone phase flag).
__global__ void __launch_bounds__(1024, 1) scan_kernel(
        const float* __restrict__ xp, const float* __restrict__ h12,
        const float* __restrict__ tagx,
        const float* __restrict__ Whh11, const float* __restrict__ Wih21,
        const float* __restrict__ Whh21, const float* __restrict__ b21,
        const float* __restrict__ Wtag,
        float* __restrict__ h1b0, float* __restrict__ h1b1,
        float* __restrict__ h2b0, float* __restrict__ h2b1,
        int* __restrict__ bar, float* __restrict__ out) {
    __shared__ float h1s[16 * Hn];          // 48 KB
    __shared__ float h2s[16 * Hn];          // 48 KB
    __shared__ float wt1[Hn], wt2[Hn];      // 6 KB
    __shared__ float redbuf[16][16][2][16]; // 32 KB [w'][m][acc][j]

    const int tid  = threadIdx.x;
    const int wv   = tid >> 6;          // wave 0..15  (owns batch m=wv)
    const int lane = tid & 63;
    const int j    = lane & 15;
    const int ksl  = lane >> 4;         // 0..3
    const int ks   = wv * 4 + ksl;      // 0..63 -> k in [ks*12, ks*12+12)
    const int kb   = ks * 12;
    const int bgp  = blockIdx.x / 48;
    const int cgp  = blockIdx.x % 48;
    const int col  = cgp * 16 + j;
    const int myb  = bgp * 16 + wv;     // global batch this wave owns

    // loop-invariant: weight slices (9 float4)
    float4 w11r[3], w21r[3], w2hr[3];
    {
        const float* p1 = Whh11 + (size_t)col * Hn + kb;
        const float* p2 = Wih21 + (size_t)col * Hn + kb;
        const float* p3 = Whh21 + (size_t)col * Hn + kb;
        #pragma unroll
        for (int q = 0; q < 3; ++q) {
            w11r[q] = *(const float4*)(p1 + q * 4);
            w21r[q] = *(const float4*)(p2 + q * 4);
            w2hr[q] = *(const float4*)(p3 + q * 4);
        }
    }
    for (int i = tid; i < Hn; i += 1024) { wt1[i] = Wtag[i]; wt2[i] = Wtag[Hn + i]; }
    const float bias21 = b21[col];

    // barrier bookkeeping for this batch-group
    int* cnt  = bar + bgp * 64;
    int* flag = bar + bgp * 64 + 32;

    float h2c = 0.f;                    // fp32 carry, valid in lanes < 16
    float* outO   = out;
    float* outH2  = out + RTn;
    float* outTag = out + RTn + (size_t)RTn * Hn;
    const size_t srcbase = (size_t)bgp * 16 * Hn;
    const float* xprow  = xp  + ((size_t)myb * Tn) * Hn + col;
    const float* h12row = h12 + ((size_t)myb * Tn) * Hn + col;
    const float* tgxrow = tagx + (size_t)myb * Tn;
    __syncthreads();

    for (int t = 0; t < Tn; ++t) {
        const float* h1c = (t & 1) ? h1b1 : h1b0;
        const float* h2c_g = (t & 1) ? h2b1 : h2b0;
        float* h1n = (t & 1) ? h1b0 : h1b1;
        float* h2n = (t & 1) ? h2b0 : h2b1;

        // prefetch (used in epilogue): lanes < 16 of each wave
        float xpv = 0.f, h12pv = 0.f;
        if (lane < 16) {
            xpv   = xprow [(size_t)t * Hn];
            h12pv = h12row[(size_t)t * Hn];
        }
        const float tgx = tgxrow[t];

        // phase A: flat-stage 16x768 fp32 h1,h2 into LDS (3 float4 each)
        #pragma unroll
        for (int i = 0; i < 3; ++i) {
            int c4 = (tid + i * 1024) * 4;
            *(float4*)&h1s[c4] = *(const float4*)(h1c   + srcbase + c4);
            *(float4*)&h2s[c4] = *(const float4*)(h2c_g + srcbase + c4);
        }
        __syncthreads();

        // phase B: tag gate for batch wv; lane covers k = lane*12..+12
        float tg;
        {
            float s0 = 0.f, s1 = 0.f, s2 = 0.f, s3 = 0.f;
            const int k0 = lane * 12;
            #pragma unroll
            for (int q = 0; q < 3; ++q) {
                float4 x1 = *(const float4*)&h1s[wv * Hn + k0 + q * 4];
                float4 x2 = *(const float4*)&h2s[wv * Hn + k0 + q * 4];
                float4 u1 = *(const float4*)&wt1[k0 + q * 4];
                float4 u2 = *(const float4*)&wt2[k0 + q * 4];
                s0 = fmaf(x1.x, u1.x, s0); s1 = fmaf(x1.y, u1.y, s1);
                s2 = fmaf(x1.z, u1.z, s2); s3 = fmaf(x1.w, u1.w, s3);
                s0 = fmaf(x2.x, u2.x, s0); s1 = fmaf(x2.y, u2.y, s1);
                s2 = fmaf(x2.z, u2.z, s2); s3 = fmaf(x2.w, u2.w, s3);
            }
            float s = (s0 + s1) + (s2 + s3);
            #pragma unroll
            for (int m = 1; m < 64; m <<= 1) s += __shfl_xor(s, m, 64);
            tg = tgx + s;
        }

        // phase C: matvec partials, 16 batches, register weights
        #pragma unroll 4
        for (int b = 0; b < 16; ++b) {
            const float* r1 = &h1s[b * Hn + kb];
            const float* r2 = &h2s[b * Hn + kb];
            float a0 = 0.f, a1 = 0.f, a2 = 0.f, a3 = 0.f;
            float c0 = 0.f, c1 = 0.f, c2 = 0.f, c3 = 0.f;
            float d0 = 0.f, d1 = 0.f, d2 = 0.f, d3 = 0.f;
            #pragma unroll
            for (int q = 0; q < 3; ++q) {
                float4 x1 = *(const float4*)(r1 + q * 4);
                float4 x2 = *(const float4*)(r2 + q * 4);
                a0 = fmaf(x1.x, w11r[q].x, a0); a1 = fmaf(x1.y, w11r[q].y, a1);
                a2 = fmaf(x1.z, w11r[q].z, a2); a3 = fmaf(x1.w, w11r[q].w, a3);
                c0 = fmaf(x1.x, w21r[q].x, c0); c1 = fmaf(x1.y, w21r[q].y, c1);
                c2 = fmaf(x1.z, w21r[q].z, c2); c3 = fmaf(x1.w, w21r[q].w, c3);
                d0 = fmaf(x2.x, w2hr[q].x, d0); d1 = fmaf(x2.y, w2hr[q].y, d1);
                d2 = fmaf(x2.z, w2hr[q].z, d2); d3 = fmaf(x2.w, w2hr[q].w, d3);
            }
            float a11 = (a0 + a1) + (a2 + a3);
            float a21 = ((c0 + c1) + (c2 + c3)) + ((d0 + d1) + (d2 + d3));
            a11 += __shfl_xor(a11, 16, 64); a11 += __shfl_xor(a11, 32, 64);
            a21 += __shfl_xor(a21, 16, 64); a21 += __shfl_xor(a21, 32, 64);
            if (lane < 16) {
                redbuf[wv][b][0][j] = a11;
                redbuf[wv][b][1][j] = a21;
            }
        }
        __syncthreads();

        // phase D: wave wv finishes batch wv (lanes < 16)
        if (lane < 16) {
            float f11 = 0.f, f21 = 0.f;
            #pragma unroll
            for (int w = 0; w < 16; ++w) {
                f11 += redbuf[w][wv][0][j];
                f21 += redbuf[w][wv][1][j];
            }
            float o    = 1.f / (1.f + expf(-tg));
            float h11v = tanhf(xpv + f11);
            float h21v = tanhf(f21 + bias21);
            float h1nv = h11v * (1.f - o) + h12pv * o;
            float h2nv = h2c * (1.f - o) + h21v * o;
            h2c = h2nv;
            size_t rr = (size_t)myb * Tn + t;
            h1n[(size_t)myb * Hn + col] = h1nv;
            h2n[(size_t)myb * Hn + col] = h2nv;
            outH2[rr * Hn + col] = h2nv;
            if (lane == 0 && cgp == 0) { outO[rr] = o; outTag[rr] = tg; }
        }

        // per-group barrier (48 blocks), monotone phase = t+1
        __threadfence();
        __syncthreads();
        if (tid == 0) {
            int old = __hip_atomic_fetch_add(cnt, 1, __ATOMIC_ACQ_REL,
                                             __HIP_MEMORY_SCOPE_AGENT);
            if (old == 47) {
                __hip_atomic_store(cnt, 0, __ATOMIC_RELAXED, __HIP_MEMORY_SCOPE_AGENT);
                __hip_atomic_store(flag, t + 1, __ATOMIC_RELEASE, __HIP_MEMORY_SCOPE_AGENT);
            } else {
                while (__hip_atomic_load(flag, __ATOMIC_ACQUIRE,
                                         __HIP_MEMORY_SCOPE_AGENT) < t + 1)
                    __builtin_amdgcn_s_sleep(4);
            }
            __threadfence();
        }
        __syncthreads();
    }
}

// ---------------------------------------------------------------------------
extern "C" void kernel_launch(void* const* d_in, const int* in_sizes, int n_in,
                              void* d_out, int out_size, void* d_ws, size_t ws_size,
                              hipStream_t stream) {
    const float* bert  = (const float*)d_in[0];
    const float* Wih11 = (const float*)d_in[1];
    const float* Whh11 = (const float*)d_in[2];
    const float* b11   = (const float*)d_in[3];
    const float* Wih12 = (const float*)d_in[4];
    const float* Whh12 = (const float*)d_in[5];
    const float* b12   = (const float*)d_in[6];
    const float* Wih21 = (const float*)d_in[7];
    const float* Whh21 = (const float*)d_in[8];
    const float* b21   = (const float*)d_in[9];
    const float* Wtag  = (const float*)d_in[10];
    const float* btag  = (const float*)d_in[11];
    const float* hinit = (const float*)d_in[12];
    float* ws = (float*)d_ws;
    float* xp   = ws + OFF_XP;
    float* h12  = ws + OFF_H12;
    float* tagx = ws + OFF_TAGX;
    float* c12  = ws + OFF_C12;
    float* h1b0 = ws + OFF_H1B0;
    float* h1b1 = ws + OFF_H1B1;
    float* h2b0 = ws + OFF_H2B0;
    float* h2b1 = ws + OFF_H2B1;
    int*   bar  = (int*)(ws + OFF_BAR);
    float* out  = (float*)d_out;

    hipMemsetAsync(h1b0, 0, (size_t)Bn * Hn * sizeof(float), stream);
    hipMemsetAsync(h2b0, 0, (size_t)Bn * Hn * sizeof(float), stream);
    hipMemsetAsync(bar,  0, 4 * 64 * sizeof(int), stream);   // re-zeroed every launch

    c12_kernel<<<3, 256, 0, stream>>>(Whh12, hinit, b12, c12);
    gemm_pre<<<256 * 24, 256, 0, stream>>>(bert, Wih11, Wih12, b11, c12, xp, h12);
    tagx_kernel<<<RTn / 4, 256, 0, stream>>>(bert, Wtag, btag, tagx);

    void* params[] = { &xp, &h12, &tagx, &Whh11, &Wih21, &Whh21, &b21, &Wtag,
                       &h1b0, &h1b1, &h2b0, &h2b1, &bar, &out };
    hipLaunchCooperativeKernel((void*)scan_kernel, dim3(192), dim3(1024),
                               params, 0, stream);
}

// Round 5
// 10331.694 us; speedup vs baseline: 4.0657x; 4.0657x over previous
//
#include <hip/hip_runtime.h>
#include <math.h>

constexpr int Bn = 64;
constexpr int Tn = 512;
constexpr int Hn = 768;
constexpr int RTn = Bn * Tn;               // 32768 rows

constexpr int NPROD = 48;                  // col-blocks per group
constexpr int NGRP  = 4;                   // batch groups (16 batches each)
constexpr int SLOTS = 4;                   // publish ring depth
constexpr int GSTR  = NPROD * 512;         // floats per group per slot (48*16*2*16)
constexpr int SSTR  = NGRP * GSTR;         // floats per slot

// workspace offsets (in floats)
constexpr size_t OFF_XP    = 0;
constexpr size_t OFF_H12   = OFF_XP  + (size_t)RTn * Hn;
constexpr size_t OFF_TAGX  = OFF_H12 + (size_t)RTn * Hn;
constexpr size_t OFF_C12   = OFF_TAGX + (size_t)RTn;
constexpr size_t OFF_PUB   = OFF_C12  + Hn;
constexpr size_t OFF_FLAGS = OFF_PUB  + (size_t)SLOTS * SSTR;  // int region

// ---------------------------------------------------------------------------
__global__ void __launch_bounds__(256) c12_kernel(const float* __restrict__ Whh12,
                                                  const float* __restrict__ hinit,
                                                  const float* __restrict__ b12,
                                                  float* __restrict__ c12) {
    int j = blockIdx.x * 256 + threadIdx.x;
    if (j >= Hn) return;
    float s = b12[j];
    const float* row = Whh12 + (size_t)j * Hn;
    for (int e = 0; e < Hn; ++e) s += row[e] * hinit[e];
    c12[j] = s;
}

// ---------------------------------------------------------------------------
__global__ void __launch_bounds__(256) tagx_kernel(const float* __restrict__ bert,
                                                   const float* __restrict__ Wtag,
                                                   const float* __restrict__ btag,
                                                   float* __restrict__ tagx) {
    int r = blockIdx.x * 4 + (threadIdx.x >> 6);
    int lane = threadIdx.x & 63;
    const float* wx = Wtag + 2 * Hn;
    const float* row = bert + (size_t)r * Hn;
    float s = 0.f;
    for (int e = lane; e < Hn; e += 64) s += row[e] * wx[e];
    #pragma unroll
    for (int m = 1; m < 64; m <<= 1) s += __shfl_xor(s, m, 64);
    if (lane == 0) tagx[r] = s + btag[0];
}

// ---------------------------------------------------------------------------
// Precompute GEMM (fp32): xp11 and tanh'ed h12_seq.
__global__ void __launch_bounds__(256) gemm_pre(const float* __restrict__ bert,
                                                const float* __restrict__ Wih11,
                                                const float* __restrict__ Wih12,
                                                const float* __restrict__ b11,
                                                const float* __restrict__ c12,
                                                float* __restrict__ xp,
                                                float* __restrict__ h12) {
    constexpr int BM = 128, BN = 64, BK = 16;
    __shared__ float As[BK][BM];
    __shared__ float Ws[BK][BN];
    const int bid = blockIdx.x;
    const int mt = bid / 24, nt = bid % 24;
    const int r0 = mt * BM;
    const int n0 = nt * BN;
    const bool second = (n0 >= Hn);
    const float* W = second ? Wih12 : Wih11;
    const int jbase = second ? (n0 - Hn) : n0;
    const int tid = threadIdx.x;
    const int ty = tid >> 4, tx = tid & 15;
    const int lrow = tid >> 1, lhalf = (tid & 1) * 8;
    const int wjl = tid & 63, wkk = tid >> 6;
    float acc[8][4] = {};
    for (int e0 = 0; e0 < Hn; e0 += BK) {
        float4 av0 = *(const float4*)(bert + (size_t)(r0 + lrow) * Hn + e0 + lhalf);
        float4 av1 = *(const float4*)(bert + (size_t)(r0 + lrow) * Hn + e0 + lhalf + 4);
        float4 wv  = *(const float4*)(W + (size_t)(jbase + wjl) * Hn + e0 + wkk * 4);
        As[lhalf + 0][lrow] = av0.x; As[lhalf + 1][lrow] = av0.y;
        As[lhalf + 2][lrow] = av0.z; As[lhalf + 3][lrow] = av0.w;
        As[lhalf + 4][lrow] = av1.x; As[lhalf + 5][lrow] = av1.y;
        As[lhalf + 6][lrow] = av1.z; As[lhalf + 7][lrow] = av1.w;
        Ws[wkk * 4 + 0][wjl] = wv.x; Ws[wkk * 4 + 1][wjl] = wv.y;
        Ws[wkk * 4 + 2][wjl] = wv.z; Ws[wkk * 4 + 3][wjl] = wv.w;
        __syncthreads();
        #pragma unroll
        for (int k = 0; k < BK; ++k) {
            float a[8], w[4];
            *(float4*)&a[0] = *(const float4*)&As[k][ty * 8];
            *(float4*)&a[4] = *(const float4*)&As[k][ty * 8 + 4];
            *(float4*)&w[0] = *(const float4*)&Ws[k][tx * 4];
            #pragma unroll
            for (int ii = 0; ii < 8; ++ii)
                #pragma unroll
                for (int jj = 0; jj < 4; ++jj)
                    acc[ii][jj] += a[ii] * w[jj];
        }
        __syncthreads();
    }
    #pragma unroll
    for (int ii = 0; ii < 8; ++ii) {
        size_t r = (size_t)(r0 + ty * 8 + ii);
        if (!second) {
            #pragma unroll
            for (int jj = 0; jj < 4; ++jj) {
                int n = n0 + tx * 4 + jj;
                xp[r * Hn + n] = acc[ii][jj] + b11[n];
            }
        } else {
            #pragma unroll
            for (int jj = 0; jj < 4; ++jj) {
                int n = n0 - Hn + tx * 4 + jj;
                h12[r * Hn + n] = tanhf(acc[ii][jj] + c12[n]);
            }
        }
    }
}

// ---------------------------------------------------------------------------
// Dataflow scan: 192 blocks = 4 groups(16 batches) x 48 col-blocks(16 cols),
// 512 threads (8 waves). No barrier: each block publishes its 2KB state slice
// to a depth-4 ring + sets a monotone per-producer seq flag; consumers spin
// on the 48 flags (48 parallel spinner threads) then gather 96KB from L3.
// Weights register-stationary (72 VGPR). All math fp32 (identical to R3).
__global__ void __launch_bounds__(512, 1) scan_kernel(
        const float* __restrict__ xp, const float* __restrict__ h12,
        const float* __restrict__ tagx,
        const float* __restrict__ Whh11, const float* __restrict__ Wih21,
        const float* __restrict__ Whh21, const float* __restrict__ b21,
        const float* __restrict__ Wtag,
        float* __restrict__ pub, int* __restrict__ flags,
        float* __restrict__ out) {
    __shared__ float h1s[16 * 772];         // padded rows (bank spread)
    __shared__ float h2s[16 * 772];
    __shared__ float wt1[Hn], wt2[Hn];
    __shared__ float redbuf[8][16][2][16];  // [wave][batch][{a11,a21}][j]
    __shared__ float tagbuf[16];

    const int tid  = threadIdx.x;
    const int wv   = tid >> 6;          // wave 0..7
    const int lane = tid & 63;
    const int bid  = blockIdx.x;
    const int xcd  = bid & 7;
    const int g    = xcd >> 1;                       // group 0..3 (2 XCDs each)
    const int prod = ((bid >> 3) << 1) | (xcd & 1);  // col-block 0..47
    const int j    = tid & 15;          // col-local
    const int ks   = tid >> 4;          // k-slice 0..31 -> k in [ks*24, ks*24+24)
    const int col  = prod * 16 + j;

    // loop-invariant: weight slices (18 float4 = 72 VGPR)
    float4 w11r[6], w21r[6], w2hr[6];
    {
        const float* p1 = Whh11 + (size_t)col * Hn + ks * 24;
        const float* p2 = Wih21 + (size_t)col * Hn + ks * 24;
        const float* p3 = Whh21 + (size_t)col * Hn + ks * 24;
        #pragma unroll
        for (int q = 0; q < 6; ++q) {
            w11r[q] = *(const float4*)(p1 + q * 4);
            w21r[q] = *(const float4*)(p2 + q * 4);
            w2hr[q] = *(const float4*)(p3 + q * 4);
        }
    }
    for (int i = tid; i < Hn; i += 512) { wt1[i] = Wtag[i]; wt2[i] = Wtag[Hn + i]; }
    const float bias21 = b21[col];

    float* outO   = out;
    float* outH2  = out + RTn;
    float* outTag = out + RTn + (size_t)RTn * Hn;
    int* myflag = flags + (g * NPROD + prod) * 16;
    __syncthreads();

    for (int t = 0; t < Tn; ++t) {
        // flag-independent prefetch (issued before the spin)
        float xpv = 0.f, h12pv = 0.f, tgxv = 0.f;
        if (tid < 256) {
            int m = tid >> 4;
            size_t rr = (size_t)(g * 16 + m) * Tn + t;
            xpv   = xp  [rr * Hn + col];
            h12pv = h12 [rr * Hn + col];
            tgxv  = tagx[rr];
        }

        // wait for all 48 producers' state_t (48 parallel spinners)
        if (tid < NPROD) {
            const int* f = flags + (g * NPROD + tid) * 16;
            while (__hip_atomic_load(f, __ATOMIC_ACQUIRE,
                                     __HIP_MEMORY_SCOPE_AGENT) < t)
                __builtin_amdgcn_s_sleep(1);
        }
        __syncthreads();

        // phase A: gather state_t (48 x 2KB) into LDS
        const float* pubc = pub + (size_t)(t & 3) * SSTR + g * GSTR;
        #pragma unroll
        for (int i = 0; i < 12; ++i) {
            int idx4 = tid + i * 512;
            int f4 = idx4 & 3, a = (idx4 >> 2) & 1;
            int b = (idx4 >> 3) & 15, p = idx4 >> 7;
            float4 v = *(const float4*)(pubc + p * 512 + b * 32 + a * 16 + f4 * 4);
            float* dst = a ? h2s : h1s;
            *(float4*)&dst[b * 772 + p * 16 + f4 * 4] = v;
        }
        __syncthreads();

        // phase B: tag gate, wave wv handles batches 2wv, 2wv+1
        #pragma unroll
        for (int ml = 0; ml < 2; ++ml) {
            int m = wv * 2 + ml;
            const int k0 = lane * 12;
            float s0 = 0.f, s1 = 0.f, s2 = 0.f, s3 = 0.f;
            #pragma unroll
            for (int q = 0; q < 3; ++q) {
                float4 x1 = *(const float4*)&h1s[m * 772 + k0 + q * 4];
                float4 x2 = *(const float4*)&h2s[m * 772 + k0 + q * 4];
                float4 u1 = *(const float4*)&wt1[k0 + q * 4];
                float4 u2 = *(const float4*)&wt2[k0 + q * 4];
                s0 = fmaf(x1.x, u1.x, s0); s1 = fmaf(x1.y, u1.y, s1);
                s2 = fmaf(x1.z, u1.z, s2); s3 = fmaf(x1.w, u1.w, s3);
                s0 = fmaf(x2.x, u2.x, s0); s1 = fmaf(x2.y, u2.y, s1);
                s2 = fmaf(x2.z, u2.z, s2); s3 = fmaf(x2.w, u2.w, s3);
            }
            float s = (s0 + s1) + (s2 + s3);
            #pragma unroll
            for (int mm = 1; mm < 64; mm <<= 1) s += __shfl_xor(s, mm, 64);
            if (lane == 0) tagbuf[m] = s;
        }

        // phase C: matvec partials over this thread's 24-k slice, 16 batches
        #pragma unroll 4
        for (int b = 0; b < 16; ++b) {
            const float* r1 = &h1s[b * 772 + ks * 24];
            const float* r2 = &h2s[b * 772 + ks * 24];
            float a0 = 0.f, a1 = 0.f, a2 = 0.f, a3 = 0.f;
            float c0 = 0.f, c1 = 0.f, c2 = 0.f, c3 = 0.f;
            float d0 = 0.f, d1 = 0.f, d2 = 0.f, d3 = 0.f;
            #pragma unroll
            for (int q = 0; q < 6; ++q) {
                float4 x1 = *(const float4*)(r1 + q * 4);
                float4 x2 = *(const float4*)(r2 + q * 4);
                a0 = fmaf(x1.x, w11r[q].x, a0); a1 = fmaf(x1.y, w11r[q].y, a1);
                a2 = fmaf(x1.z, w11r[q].z, a2); a3 = fmaf(x1.w, w11r[q].w, a3);
                c0 = fmaf(x1.x, w21r[q].x, c0); c1 = fmaf(x1.y, w21r[q].y, c1);
                c2 = fmaf(x1.z, w21r[q].z, c2); c3 = fmaf(x1.w, w21r[q].w, c3);
                d0 = fmaf(x2.x, w2hr[q].x, d0); d1 = fmaf(x2.y, w2hr[q].y, d1);
                d2 = fmaf(x2.z, w2hr[q].z, d2); d3 = fmaf(x2.w, w2hr[q].w, d3);
            }
            float a11 = (a0 + a1) + (a2 + a3);
            float a21 = ((c0 + c1) + (c2 + c3)) + ((d0 + d1) + (d2 + d3));
            a11 += __shfl_xor(a11, 16, 64); a11 += __shfl_xor(a11, 32, 64);
            a21 += __shfl_xor(a21, 16, 64); a21 += __shfl_xor(a21, 32, 64);
            if (lane < 16) {
                redbuf[wv][b][0][j] = a11;
                redbuf[wv][b][1][j] = a21;
            }
        }
        __syncthreads();

        // phase D: 256 threads = (batch m, col j); gate + update + publish
        if (tid < 256) {
            int m = tid >> 4;
            float f11 = 0.f, f21 = 0.f;
            #pragma unroll
            for (int w = 0; w < 8; ++w) {
                f11 += redbuf[w][m][0][j];
                f21 += redbuf[w][m][1][j];
            }
            float tg   = tagbuf[m] + tgxv;
            float o    = 1.f / (1.f + expf(-tg));
            float h11v = tanhf(xpv + f11);
            float h21v = tanhf(f21 + bias21);
            float h2pv = h2s[m * 772 + prod * 16 + j];
            float h1nv = h11v * (1.f - o) + h12pv * o;
            float h2nv = h2pv * (1.f - o) + h21v * o;
            float* pn = pub + (size_t)((t + 1) & 3) * SSTR + g * GSTR
                      + prod * 512 + m * 32;
            pn[j]      = h1nv;
            pn[16 + j] = h2nv;
            size_t rr = (size_t)(g * 16 + m) * Tn + t;
            outH2[rr * Hn + col] = h2nv;
            if (j == 0 && prod == 0) { outO[rr] = o; outTag[rr] = tg; }
        }
        __syncthreads();            // all waves' publish stores drained (vmcnt 0)
        if (tid == 0) {
            __threadfence();        // L2 writeback -> L3-visible
            __hip_atomic_store(myflag, t + 1, __ATOMIC_RELAXED,
                               __HIP_MEMORY_SCOPE_AGENT);
        }
    }
}

// ---------------------------------------------------------------------------
extern "C" void kernel_launch(void* const* d_in, const int* in_sizes, int n_in,
                              void* d_out, int out_size, void* d_ws, size_t ws_size,
                              hipStream_t stream) {
    const float* bert  = (const float*)d_in[0];
    const float* Wih11 = (const float*)d_in[1];
    const float* Whh11 = (const float*)d_in[2];
    const float* b11   = (const float*)d_in[3];
    const float* Wih12 = (const float*)d_in[4];
    const float* Whh12 = (const float*)d_in[5];
    const float* b12   = (const float*)d_in[6];
    const float* Wih21 = (const float*)d_in[7];
    const float* Whh21 = (const float*)d_in[8];
    const float* b21   = (const float*)d_in[9];
    const float* Wtag  = (const float*)d_in[10];
    const float* btag  = (const float*)d_in[11];
    const float* hinit = (const float*)d_in[12];
    float* ws = (float*)d_ws;
    float* xp    = ws + OFF_XP;
    float* h12   = ws + OFF_H12;
    float* tagx  = ws + OFF_TAGX;
    float* c12   = ws + OFF_C12;
    float* pub   = ws + OFF_PUB;
    int*   flags = (int*)(ws + OFF_FLAGS);
    float* out   = (float*)d_out;

    // zero publish ring (slot 0 = initial h=0 state) and seq flags
    hipMemsetAsync(pub,   0, (size_t)SLOTS * SSTR * sizeof(float), stream);
    hipMemsetAsync(flags, 0, NGRP * NPROD * 16 * sizeof(int), stream);

    c12_kernel<<<3, 256, 0, stream>>>(Whh12, hinit, b12, c12);
    gemm_pre<<<256 * 24, 256, 0, stream>>>(bert, Wih11, Wih12, b11, c12, xp, h12);
    tagx_kernel<<<RTn / 4, 256, 0, stream>>>(bert, Wtag, btag, tagx);

    void* params[] = { &xp, &h12, &tagx, &Whh11, &Wih21, &Whh21, &b21, &Wtag,
                       &pub, &flags, &out };
    hipLaunchCooperativeKernel((void*)scan_kernel, dim3(192), dim3(512),
                               params, 0, stream);
}

// Round 6
// 5372.379 us; speedup vs baseline: 7.8188x; 1.9231x over previous
//
#include <hip/hip_runtime.h>
#include <math.h>

constexpr int Bn = 64;
constexpr int Tn = 512;
constexpr int Hn = 768;
constexpr int RTn = Bn * Tn;               // 32768 rows

constexpr int NPROD = 24;                  // col-blocks per group (one XCD)
constexpr int NGRP  = 8;                   // batch groups (8 batches each)
constexpr int SLOTS = 4;                   // publish ring depth
constexpr int GSTR  = NPROD * 512;         // floats per group per slot (24*8*2*32)
constexpr int SSTR  = NGRP * GSTR;         // floats per slot
constexpr int FSTR  = 32;                  // flag stride (ints) = 128B line
constexpr int ROWF  = 772;                 // LDS row stride (768 + 4 pad)

// workspace offsets (in floats)
constexpr size_t OFF_XP    = 0;
constexpr size_t OFF_H12   = OFF_XP  + (size_t)RTn * Hn;
constexpr size_t OFF_TAGX  = OFF_H12 + (size_t)RTn * Hn;
constexpr size_t OFF_C12   = OFF_TAGX + (size_t)RTn;
constexpr size_t OFF_PUB   = OFF_C12  + Hn;
constexpr size_t OFF_FLAGS = OFF_PUB  + (size_t)SLOTS * SSTR;  // int region

// ---------------------------------------------------------------------------
__global__ void __launch_bounds__(256) c12_kernel(const float* __restrict__ Whh12,
                                                  const float* __restrict__ hinit,
                                                  const float* __restrict__ b12,
                                                  float* __restrict__ c12) {
    int j = blockIdx.x * 256 + threadIdx.x;
    if (j >= Hn) return;
    float s = b12[j];
    const float* row = Whh12 + (size_t)j * Hn;
    for (int e = 0; e < Hn; ++e) s += row[e] * hinit[e];
    c12[j] = s;
}

// ---------------------------------------------------------------------------
__global__ void __launch_bounds__(256) tagx_kernel(const float* __restrict__ bert,
                                                   const float* __restrict__ Wtag,
                                                   const float* __restrict__ btag,
                                                   float* __restrict__ tagx) {
    int r = blockIdx.x * 4 + (threadIdx.x >> 6);
    int lane = threadIdx.x & 63;
    const float* wx = Wtag + 2 * Hn;
    const float* row = bert + (size_t)r * Hn;
    float s = 0.f;
    for (int e = lane; e < Hn; e += 64) s += row[e] * wx[e];
    #pragma unroll
    for (int m = 1; m < 64; m <<= 1) s += __shfl_xor(s, m, 64);
    if (lane == 0) tagx[r] = s + btag[0];
}

// ---------------------------------------------------------------------------
// Precompute GEMM (fp32): xp11 and tanh'ed h12_seq.
__global__ void __launch_bounds__(256) gemm_pre(const float* __restrict__ bert,
                                                const float* __restrict__ Wih11,
                                                const float* __restrict__ Wih12,
                                                const float* __restrict__ b11,
                                                const float* __restrict__ c12,
                                                float* __restrict__ xp,
                                                float* __restrict__ h12) {
    constexpr int BM = 128, BN = 64, BK = 16;
    __shared__ float As[BK][BM];
    __shared__ float Ws[BK][BN];
    const int bid = blockIdx.x;
    const int mt = bid / 24, nt = bid % 24;
    const int r0 = mt * BM;
    const int n0 = nt * BN;
    const bool second = (n0 >= Hn);
    const float* W = second ? Wih12 : Wih11;
    const int jbase = second ? (n0 - Hn) : n0;
    const int tid = threadIdx.x;
    const int ty = tid >> 4, tx = tid & 15;
    const int lrow = tid >> 1, lhalf = (tid & 1) * 8;
    const int wjl = tid & 63, wkk = tid >> 6;
    float acc[8][4] = {};
    for (int e0 = 0; e0 < Hn; e0 += BK) {
        float4 av0 = *(const float4*)(bert + (size_t)(r0 + lrow) * Hn + e0 + lhalf);
        float4 av1 = *(const float4*)(bert + (size_t)(r0 + lrow) * Hn + e0 + lhalf + 4);
        float4 wv  = *(const float4*)(W + (size_t)(jbase + wjl) * Hn + e0 + wkk * 4);
        As[lhalf + 0][lrow] = av0.x; As[lhalf + 1][lrow] = av0.y;
        As[lhalf + 2][lrow] = av0.z; As[lhalf + 3][lrow] = av0.w;
        As[lhalf + 4][lrow] = av1.x; As[lhalf + 5][lrow] = av1.y;
        As[lhalf + 6][lrow] = av1.z; As[lhalf + 7][lrow] = av1.w;
        Ws[wkk * 4 + 0][wjl] = wv.x; Ws[wkk * 4 + 1][wjl] = wv.y;
        Ws[wkk * 4 + 2][wjl] = wv.z; Ws[wkk * 4 + 3][wjl] = wv.w;
        __syncthreads();
        #pragma unroll
        for (int k = 0; k < BK; ++k) {
            float a[8], w[4];
            *(float4*)&a[0] = *(const float4*)&As[k][ty * 8];
            *(float4*)&a[4] = *(const float4*)&As[k][ty * 8 + 4];
            *(float4*)&w[0] = *(const float4*)&Ws[k][tx * 4];
            #pragma unroll
            for (int ii = 0; ii < 8; ++ii)
                #pragma unroll
                for (int jj = 0; jj < 4; ++jj)
                    acc[ii][jj] += a[ii] * w[jj];
        }
        __syncthreads();
    }
    #pragma unroll
    for (int ii = 0; ii < 8; ++ii) {
        size_t r = (size_t)(r0 + ty * 8 + ii);
        if (!second) {
            #pragma unroll
            for (int jj = 0; jj < 4; ++jj) {
                int n = n0 + tx * 4 + jj;
                xp[r * Hn + n] = acc[ii][jj] + b11[n];
            }
        } else {
            #pragma unroll
            for (int jj = 0; jj < 4; ++jj) {
                int n = n0 - Hn + tx * 4 + jj;
                h12[r * Hn + n] = tanhf(acc[ii][jj] + c12[n]);
            }
        }
    }
}

// ---------------------------------------------------------------------------
// Dataflow scan v2: 192 blocks = 8 groups(8 batches, 1 XCD under round-robin)
// x 24 col-blocks(32 cols). 1024 threads (16 waves, 4/SIMD). Publish = relaxed
// agent-scope atomic stores (device-coherent write-through; NO buffer_wbl2),
// drained by __syncthreads' vmcnt(0), then relaxed atomic flag. Gather =
// relaxed agent-scope atomic loads. Weights register-stationary (72 VGPR).
__global__ void __launch_bounds__(1024, 1) scan_kernel(
        const float* __restrict__ xp, const float* __restrict__ h12,
        const float* __restrict__ tagx,
        const float* __restrict__ Whh11, const float* __restrict__ Wih21,
        const float* __restrict__ Whh21, const float* __restrict__ b21,
        const float* __restrict__ Wtag,
        float* __restrict__ pub, int* __restrict__ flags,
        float* __restrict__ out) {
    __shared__ float h1s[8 * ROWF];          // 24.7 KB
    __shared__ float h2s[8 * ROWF];
    __shared__ float wt1[Hn], wt2[Hn];       // 6 KB
    __shared__ float redbuf[16][8][2][32];   // 32 KB [wave][batch][acc][j]
    __shared__ float tagbuf[8];

    const int tid  = threadIdx.x;
    const int wv   = tid >> 6;          // wave 0..15
    const int lane = tid & 63;
    const int bid  = blockIdx.x;
    const int g    = bid & 7;           // group = XCD (round-robin heuristic)
    const int prod = bid >> 3;          // col-block 0..23
    const int j    = tid & 31;          // col-local 0..31
    const int ks   = tid >> 5;          // k-slice 0..31 -> k in [ks*24, ks*24+24)
    const int col  = prod * 32 + j;

    // loop-invariant weights: 18 float4 = 72 VGPR
    float4 w11r[6], w21r[6], w2hr[6];
    {
        const float* p1 = Whh11 + (size_t)col * Hn + ks * 24;
        const float* p2 = Wih21 + (size_t)col * Hn + ks * 24;
        const float* p3 = Whh21 + (size_t)col * Hn + ks * 24;
        #pragma unroll
        for (int q = 0; q < 6; ++q) {
            w11r[q] = *(const float4*)(p1 + q * 4);
            w21r[q] = *(const float4*)(p2 + q * 4);
            w2hr[q] = *(const float4*)(p3 + q * 4);
        }
    }
    for (int i = tid; i < Hn; i += 1024) { wt1[i] = Wtag[i]; wt2[i] = Wtag[Hn + i]; }
    const float bias21 = b21[col];

    float* outO   = out;
    float* outH2  = out + RTn;
    float* outTag = out + RTn + (size_t)RTn * Hn;
    int* myflag = flags + (g * NPROD + prod) * FSTR;

    for (int t = 0; t < Tn; ++t) {
        // flag-independent prefetch (before the spin)
        float xpv = 0.f, h12pv = 0.f, tgxv = 0.f;
        if (tid < 256) {
            int m = tid >> 5;
            size_t rr = (size_t)(g * 8 + m) * Tn + t;
            xpv   = xp  [rr * Hn + col];
            h12pv = h12 [rr * Hn + col];
            tgxv  = tagx[rr];
        }

        // spin: 24 parallel pollers, one per producer flag
        if (tid < NPROD) {
            const int* f = flags + (g * NPROD + tid) * FSTR;
            while (__hip_atomic_load(f, __ATOMIC_RELAXED,
                                     __HIP_MEMORY_SCOPE_AGENT) < t)
                __builtin_amdgcn_s_sleep(2);
        }
        __syncthreads();   // A: all passed spin; prev-step LDS reads done

        // gather 48 KB (coherent loads), issue-all-then-write in 2 batches
        {
            const float* pubc = pub + (size_t)(t & 3) * SSTR + g * GSTR;
            #pragma unroll
            for (int h = 0; h < 2; ++h) {
                float tmp[6];
                #pragma unroll
                for (int i = 0; i < 6; ++i) {
                    int idx = tid + (h * 6 + i) * 1024;
                    int p = idx >> 9, rem = idx & 511;
                    int a = rem >> 8, b = (rem >> 5) & 7, c = rem & 31;
                    tmp[i] = __hip_atomic_load(
                        pubc + p * 512 + a * 256 + b * 32 + c,
                        __ATOMIC_RELAXED, __HIP_MEMORY_SCOPE_AGENT);
                }
                #pragma unroll
                for (int i = 0; i < 6; ++i) {
                    int idx = tid + (h * 6 + i) * 1024;
                    int p = idx >> 9, rem = idx & 511;
                    int a = rem >> 8, b = (rem >> 5) & 7, c = rem & 31;
                    float* dst = a ? h2s : h1s;
                    dst[b * ROWF + p * 32 + c] = tmp[i];
                }
            }
        }
        __syncthreads();   // B: state staged

        // gate: wave wv<8 handles batch wv; lane covers k = lane*12..+12
        if (wv < 8) {
            const int k0 = lane * 12;
            float s0 = 0.f, s1 = 0.f, s2 = 0.f, s3 = 0.f;
            #pragma unroll
            for (int q = 0; q < 3; ++q) {
                float4 x1 = *(const float4*)&h1s[wv * ROWF + k0 + q * 4];
                float4 x2 = *(const float4*)&h2s[wv * ROWF + k0 + q * 4];
                float4 u1 = *(const float4*)&wt1[k0 + q * 4];
                float4 u2 = *(const float4*)&wt2[k0 + q * 4];
                s0 = fmaf(x1.x, u1.x, s0); s1 = fmaf(x1.y, u1.y, s1);
                s2 = fmaf(x1.z, u1.z, s2); s3 = fmaf(x1.w, u1.w, s3);
                s0 = fmaf(x2.x, u2.x, s0); s1 = fmaf(x2.y, u2.y, s1);
                s2 = fmaf(x2.z, u2.z, s2); s3 = fmaf(x2.w, u2.w, s3);
            }
            float s = (s0 + s1) + (s2 + s3);
            #pragma unroll
            for (int mm = 1; mm < 64; mm <<= 1) s += __shfl_xor(s, mm, 64);
            if (lane == 0) tagbuf[wv] = s;
        }

        // matvec partials: 8 batches, 24-k slice per thread, register weights
        #pragma unroll 4
        for (int b = 0; b < 8; ++b) {
            const float* r1 = &h1s[b * ROWF + ks * 24];
            const float* r2 = &h2s[b * ROWF + ks * 24];
            float a0 = 0.f, a1 = 0.f, a2 = 0.f, a3 = 0.f;
            float c0 = 0.f, c1 = 0.f, c2 = 0.f, c3 = 0.f;
            float d0 = 0.f, d1 = 0.f, d2 = 0.f, d3 = 0.f;
            #pragma unroll
            for (int q = 0; q < 6; ++q) {
                float4 x1 = *(const float4*)(r1 + q * 4);
                float4 x2 = *(const float4*)(r2 + q * 4);
                a0 = fmaf(x1.x, w11r[q].x, a0); a1 = fmaf(x1.y, w11r[q].y, a1);
                a2 = fmaf(x1.z, w11r[q].z, a2); a3 = fmaf(x1.w, w11r[q].w, a3);
                c0 = fmaf(x1.x, w21r[q].x, c0); c1 = fmaf(x1.y, w21r[q].y, c1);
                c2 = fmaf(x1.z, w21r[q].z, c2); c3 = fmaf(x1.w, w21r[q].w, c3);
                d0 = fmaf(x2.x, w2hr[q].x, d0); d1 = fmaf(x2.y, w2hr[q].y, d1);
                d2 = fmaf(x2.z, w2hr[q].z, d2); d3 = fmaf(x2.w, w2hr[q].w, d3);
            }
            float a11 = (a0 + a1) + (a2 + a3);
            float a21 = ((c0 + c1) + (c2 + c3)) + ((d0 + d1) + (d2 + d3));
            a11 += __shfl_xor(a11, 32, 64);   // combine the wave's two k-slices
            a21 += __shfl_xor(a21, 32, 64);
            if (lane < 32) {
                redbuf[wv][b][0][lane] = a11;
                redbuf[wv][b][1][lane] = a21;
            }
        }
        __syncthreads();   // C: redbuf + tagbuf ready

        // epilogue: 256 threads = (batch m, col jc); publish coherent
        if (tid < 256) {
            int m = tid >> 5, jc = tid & 31;
            float f11 = 0.f, f21 = 0.f;
            #pragma unroll
            for (int w = 0; w < 16; ++w) {
                f11 += redbuf[w][m][0][jc];
                f21 += redbuf[w][m][1][jc];
            }
            float tg   = tagbuf[m] + tgxv;
            float o    = 1.f / (1.f + expf(-tg));
            float h11v = tanhf(xpv + f11);
            float h21v = tanhf(f21 + bias21);
            float h2pv = h2s[m * ROWF + prod * 32 + jc];
            float h1nv = h11v * (1.f - o) + h12pv * o;
            float h2nv = h2pv * (1.f - o) + h21v * o;
            float* pn = pub + (size_t)((t + 1) & 3) * SSTR + g * GSTR + prod * 512;
            __hip_atomic_store(pn + m * 32 + jc, h1nv,
                               __ATOMIC_RELAXED, __HIP_MEMORY_SCOPE_AGENT);
            __hip_atomic_store(pn + 256 + m * 32 + jc, h2nv,
                               __ATOMIC_RELAXED, __HIP_MEMORY_SCOPE_AGENT);
            size_t rr = (size_t)(g * 8 + m) * Tn + t;
            outH2[rr * Hn + col] = h2nv;
            if (jc == 0 && prod == 0) { outO[rr] = o; outTag[rr] = tg; }
        }
        __syncthreads();   // D: vmcnt(0) drains coherent publish stores
        if (tid == 0)
            __hip_atomic_store(myflag, t + 1, __ATOMIC_RELAXED,
                               __HIP_MEMORY_SCOPE_AGENT);
    }
}

// ---------------------------------------------------------------------------
extern "C" void kernel_launch(void* const* d_in, const int* in_sizes, int n_in,
                              void* d_out, int out_size, void* d_ws, size_t ws_size,
                              hipStream_t stream) {
    const float* bert  = (const float*)d_in[0];
    const float* Wih11 = (const float*)d_in[1];
    const float* Whh11 = (const float*)d_in[2];
    const float* b11   = (const float*)d_in[3];
    const float* Wih12 = (const float*)d_in[4];
    const float* Whh12 = (const float*)d_in[5];
    const float* b12   = (const float*)d_in[6];
    const float* Wih21 = (const float*)d_in[7];
    const float* Whh21 = (const float*)d_in[8];
    const float* b21   = (const float*)d_in[9];
    const float* Wtag  = (const float*)d_in[10];
    const float* btag  = (const float*)d_in[11];
    const float* hinit = (const float*)d_in[12];
    float* ws = (float*)d_ws;
    float* xp    = ws + OFF_XP;
    float* h12   = ws + OFF_H12;
    float* tagx  = ws + OFF_TAGX;
    float* c12   = ws + OFF_C12;
    float* pub   = ws + OFF_PUB;
    int*   flags = (int*)(ws + OFF_FLAGS);
    float* out   = (float*)d_out;

    // zero publish ring (slot 0 = initial h=0 state) and flags; dispatch
    // boundary makes these visible to the scan's coherent loads.
    hipMemsetAsync(pub,   0, (size_t)SLOTS * SSTR * sizeof(float), stream);
    hipMemsetAsync(flags, 0, NGRP * NPROD * FSTR * sizeof(int), stream);

    c12_kernel<<<3, 256, 0, stream>>>(Whh12, hinit, b12, c12);
    gemm_pre<<<256 * 24, 256, 0, stream>>>(bert, Wih11, Wih12, b11, c12, xp, h12);
    tagx_kernel<<<RTn / 4, 256, 0, stream>>>(bert, Wtag, btag, tagx);

    void* params[] = { &xp, &h12, &tagx, &Whh11, &Wih21, &Whh21, &b21, &Wtag,
                       &pub, &flags, &out };
    hipLaunchCooperativeKernel((void*)scan_kernel, dim3(192), dim3(1024),
                               params, 0, stream);
}